// Round 7
// baseline (5256.749 us; speedup 1.0000x reference)
//
#include <hip/hip_runtime.h>
#include <math.h>

// ODE-RNN forward: B=512, K=1024, U=16, P=32, H=128, L=32, TD=64
// v8: 1024 threads (16 waves) per block, 4 waves/SIMD, no redundancy.
//
// Key insight after v1-v7: three different structures (v1 6-barrier LDS-
// reduce 3455us; v4 lgkm-barriers+prefetch 3610us; v5/v7 2-barrier
// redundant-compute 3644/4054us) all pin at ~8-9.7k cy/step because total
// per-SIMD issue is invariant: same work over only 2 waves/SIMD (v1 62%
// stall) or 2x work at 2 waves/SIMD (v7, VALUBusy 65%+). v7 also proved
// bank conflicts (2e8 -> 4k) were NOT on the critical path.
// v3 proved 2 blocks/CU impossible (2x 245KB weight copies > register file).
// v8 gets 4 waves/SIMD the only legal way: ONE block of 1024 threads holding
// ONE weight copy (60 VGPR/thread), work split twice as fine:
//  - gates: j=t>>3 (unit), qg=t&7 (20-col slice: 4 x-cols + 16 h-cols);
//    8-lane DPP reduce (quad_perm xor1/xor2 + row_shl:4, silicon-proven v7).
//  - head: ho=t>>4, he=t&15 (8 h-cols); 16-lane DPP reduce (+ row_shl:8).
//  - lift: 8-lane groups, 6 cols each, DPP reduce.
//  - RK4/staging: wave 0 only (narrow, ~40 instr).
//  - hbuf padded HP2(c)=c+4*(c>>4): gate reads hit all 32 banks exactly
//    once per instr; head reads 2-way (free per m136).
// 4 lgkm-only barriers/step. h double-buffered. fp32 throughout (bf16/MFMA
// rejected: theta->y path amplifies h-error by up to 1/theta_a; y random-
// walks over 1024 steps -> absmax risk vs 0.166 threshold).

// NOTE: macro param must NOT be named `w` — (v).w would be captured.
#define DOT4(acc, v, arr, base)                                           \
  acc += (v).x * (arr)[(base)] + (v).y * (arr)[(base) + 1] +              \
         (v).z * (arr)[(base) + 2] + (v).w * (arr)[(base) + 3];

__device__ __forceinline__ float sigf(float x) {
  return 1.0f / (1.0f + __expf(-x));
}

__device__ __forceinline__ float tanh_fast(float x) {
  float ax = fabsf(x);
  float e = __expf(2.0f * ax);
  float r = 1.0f - 2.0f / (e + 1.0f);
  return copysignf(r, x);
}

// x + (x cross-lane via DPP). Pure VALU pipe.
// 0xB1 quad_perm xor1; 0x4E quad_perm xor2; 0x104 row_shl:4 (dst i <- src
// i+4, valid at row-lanes <12 — our group leaders are row-lanes 0/8);
// 0x108 row_shl:8 (valid at row-lanes <8 — leaders at row-lane 0).
template <int CTRL>
__device__ __forceinline__ float dpp_add(float x) {
  int s = __float_as_int(x);
  int r = __builtin_amdgcn_update_dpp(s, s, CTRL, 0xF, 0xF, false);
  return x + __int_as_float(r);
}

// LDS-only barrier: drains lgkmcnt but NOT vmcnt (stores/prefetch stay in
// flight). Correctness proven v2/v4/v5/v7.
#define BAR()                                            \
  do {                                                   \
    asm volatile("s_waitcnt lgkmcnt(0)" ::: "memory");   \
    __builtin_amdgcn_s_barrier();                        \
    asm volatile("" ::: "memory");                       \
  } while (0)

#define CFENCE() asm volatile("" ::: "memory")

// padded h index: +4 words after every 16 cols
#define HP2(c) ((c) + 4 * ((c) >> 4))
#define HROW 160  // 128 cols + 8*4 pad

extern "C" __global__ __launch_bounds__(1024, 4) void odernn_kernel(
    const float* __restrict__ y0, const float* __restrict__ u_seq,
    const float* __restrict__ dt_seq, const float* __restrict__ y_seq,
    const float* __restrict__ u2y, const float* __restrict__ lift_W,
    const float* __restrict__ lift_b, const float* __restrict__ w_ih,
    const float* __restrict__ w_hh, const float* __restrict__ b_ih,
    const float* __restrict__ b_hh, const float* __restrict__ head_W,
    const float* __restrict__ head_b, const int* __restrict__ tf_p,
    float* __restrict__ out_ys, float* __restrict__ out_th) {
  __shared__ __align__(16) float hbuf[2][2][HROW];  // h dbuf, HP2-padded
  __shared__ __align__(16) float xL[2][32];         // lifted x
  __shared__ __align__(16) float featL[2][48];      // [u(16)|y_in(32)]
  __shared__ float thetaL[2][64];
  __shared__ float dtL[2];
  __shared__ float liftL[32 * 49];                  // stride 49 conflict-free
  __shared__ float u2yL[512];

  const int t = threadIdx.x;
  const int wv = t >> 6;     // wave 0..15
  const int l = t & 63;
  const int b0 = blockIdx.x * 2;
  const int j = t >> 3;      // hidden unit 0..127 (8 adjacent lanes per j)
  const int qg = t & 7;      // gate col slice: x[4qg..4qg+4) + h[16qg..16qg+16)
  const int ho = t >> 4;     // head output 0..63 (16 lanes per ho)
  const int he = t & 15;     // head col slice: h[8he..8he+8)
  const int tfe = *tf_p;

  // ---- register-resident gate weights (60 floats/thread; ONE copy/block)
  float wr[20], wz[20], wn[20];
  {
    const int jr = j, jz = j + 128, jn = j + 256;
#pragma unroll
    for (int cc = 0; cc < 4; ++cc) {
      const int c = 4 * qg + cc;
      wr[cc] = w_ih[jr * 32 + c];
      wz[cc] = w_ih[jz * 32 + c];
      wn[cc] = w_ih[jn * 32 + c];
    }
#pragma unroll
    for (int cc = 0; cc < 16; ++cc) {
      const int c = 16 * qg + cc;
      wr[4 + cc] = w_hh[jr * 128 + c];
      wz[4 + cc] = w_hh[jz * 128 + c];
      wn[4 + cc] = w_hh[jn * 128 + c];
    }
  }
  float wh[8];
#pragma unroll
  for (int i = 0; i < 8; ++i) wh[i] = head_W[ho * 128 + 8 * he + i];

  const float bR = b_ih[j] + b_hh[j];
  const float bZ = b_ih[j + 128] + b_hh[j + 128];
  const float bIn = b_ih[j + 256];
  const float bHn = b_hh[j + 256];
  const float hb = head_b[ho];
  const float lb = lift_b[(t >> 3) & 31];

  for (int idx = t; idx < 32 * 48; idx += 1024)
    liftL[(idx / 48) * 49 + (idx % 48)] = lift_W[idx];
  if (t < 512) u2yL[t] = u2y[t];
  for (int idx = t; idx < 2 * 2 * HROW; idx += 1024)
    (&hbuf[0][0][0])[idx] = 0.0f;  // zero both h buffers incl. padding

  float yreg = 0.0f;
  float hreg[2] = {0.0f, 0.0f};
  float upf = 0.0f, dtpf = 0.0f;

  if (wv == 0) {
    yreg = y0[(b0 + (l >> 5)) * 32 + (l & 31)];
    // stage feat(0) directly; prefetch k=1
    if (l < 32)
      featL[l >> 4][l & 15] =
          u_seq[((size_t)(b0 + (l >> 4)) * 1024 + 0) * 16 + (l & 15)];
    if (l < 2) dtL[l] = dt_seq[(size_t)(b0 + l) * 1024 + 0];
    featL[l >> 5][16 + (l & 31)] = yreg;  // k=0: no teacher forcing
    if (l < 32)
      upf = u_seq[((size_t)(b0 + (l >> 4)) * 1024 + 1) * 16 + (l & 15)];
    if (l < 2) dtpf = dt_seq[(size_t)(b0 + l) * 1024 + 1];
  }
  __syncthreads();
  // lift x(0): 8-lane groups, 6 cols each
  if (t < 512) {
    const int o = (t >> 3) & 31, bb = t >> 8, qq = t & 7;
    float a = 0.0f;
#pragma unroll
    for (int i = 0; i < 6; ++i)
      a += featL[bb][6 * qq + i] * liftL[o * 49 + 6 * qq + i];
    a = dpp_add<0xB1>(a); a = dpp_add<0x4E>(a); a = dpp_add<0x104>(a);
    if (qq == 0) { float s = a + lb; xL[bb][o] = s * sigf(s); }
  }
  __syncthreads();
  int mtfk = 0;  // k % tfe

  for (int k = 0; k < 1024; ++k) {
    const int rp = k & 1;  // gates read hbuf[rp]=h(k-1); GRU writes hbuf[rp^1]

    // ---- gates: 4 x-cols + 16 h-cols per lane, both batches
    float aR[2], aZ[2], aI[2], aN[2];
#pragma unroll
    for (int bb = 0; bb < 2; ++bb) {
      float r_ = 0.f, z_ = 0.f, i_ = 0.f, n_ = 0.f;
      {
        float4 v = *reinterpret_cast<const float4*>(&xL[bb][4 * qg]);
        DOT4(r_, v, wr, 0)
        DOT4(z_, v, wz, 0)
        DOT4(i_, v, wn, 0)   // x-part of n-gate (i_n)
      }
      const float4* hv =
          reinterpret_cast<const float4*>(&hbuf[rp][bb][20 * qg]);  // HP2(16qg)
#pragma unroll
      for (int i = 0; i < 4; ++i) {
        float4 v = hv[i];
        DOT4(r_, v, wr, 4 + 4 * i)
        DOT4(z_, v, wz, 4 + 4 * i)
        DOT4(n_, v, wn, 4 + 4 * i)  // h-part of n-gate (h_n)
      }
      aR[bb] = r_; aZ[bb] = z_; aI[bb] = i_; aN[bb] = n_;
    }
    // 8-lane DPP reduce; full sum lands at qg==0 lanes
#pragma unroll
    for (int bb = 0; bb < 2; ++bb) {
      aR[bb] = dpp_add<0xB1>(aR[bb]); aR[bb] = dpp_add<0x4E>(aR[bb]);
      aR[bb] = dpp_add<0x104>(aR[bb]);
      aZ[bb] = dpp_add<0xB1>(aZ[bb]); aZ[bb] = dpp_add<0x4E>(aZ[bb]);
      aZ[bb] = dpp_add<0x104>(aZ[bb]);
      aI[bb] = dpp_add<0xB1>(aI[bb]); aI[bb] = dpp_add<0x4E>(aI[bb]);
      aI[bb] = dpp_add<0x104>(aI[bb]);
      aN[bb] = dpp_add<0xB1>(aN[bb]); aN[bb] = dpp_add<0x4E>(aN[bb]);
      aN[bb] = dpp_add<0x104>(aN[bb]);
    }
    if ((t & 7) == 0) {  // GRU + h update, 128 threads spread over all waves
#pragma unroll
      for (int bb = 0; bb < 2; ++bb) {
        float r = sigf(aR[bb] + bR);
        float z = sigf(aZ[bb] + bZ);
        float n = tanh_fast(aI[bb] + bIn + r * (aN[bb] + bHn));
        float hn = (1.0f - z) * n + z * hreg[bb];
        hreg[bb] = hn;
        hbuf[rp ^ 1][bb][HP2(j)] = hn;
      }
    }
    BAR();  // D: h(k) visible

    // ---- head: 8 h-cols per lane, 16-lane groups
    float s0, s1;
    {
      const int hw = HP2(8 * he);  // contiguous 8-float run
      const float4* h40 = reinterpret_cast<const float4*>(&hbuf[rp ^ 1][0][hw]);
      const float4* h41 = reinterpret_cast<const float4*>(&hbuf[rp ^ 1][1][hw]);
      float a0 = 0.f, a1 = 0.f;
#pragma unroll
      for (int i = 0; i < 2; ++i) {
        float4 v0 = h40[i];
        float4 v1 = h41[i];
        DOT4(a0, v0, wh, 4 * i)
        DOT4(a1, v1, wh, 4 * i)
      }
      s0 = a0; s1 = a1;
    }
    s0 = dpp_add<0xB1>(s0); s0 = dpp_add<0x4E>(s0);
    s0 = dpp_add<0x104>(s0); s0 = dpp_add<0x108>(s0);
    s1 = dpp_add<0xB1>(s1); s1 = dpp_add<0x4E>(s1);
    s1 = dpp_add<0x104>(s1); s1 = dpp_add<0x108>(s1);
    if (he == 0) {  // row-lane 0: full 16-lane sum valid
      float th0 = 0.001f + 1.999f * sigf(s0 + hb);
      float th1 = 0.001f + 1.999f * sigf(s1 + hb);
      thetaL[0][ho] = th0;
      thetaL[1][ho] = th1;
      out_th[((size_t)(b0 + 0) * 1024 + k) * 64 + ho] = th0;
      out_th[((size_t)(b0 + 1) * 1024 + k) * 64 + ho] = th1;
    }
    BAR();  // E: thetaL visible

    // ---- wave 0: jump + RK4 + out_ys + stage feat(k+1)
    if (wv == 0) {
      const int bb = l >> 5, jj = l & 31;
      float y = yreg;
#pragma unroll
      for (int i = 0; i < 16; ++i) y += featL[bb][i] * u2yL[i * 32 + jj];
      float a = thetaL[bb][jj];
      float b2 = thetaL[bb][32 + jj];
      float hdt = dtL[bb];
      float k1 = b2 - a * y;
      float k2 = b2 - a * (y + 0.5f * hdt * k1);
      float k3 = b2 - a * (y + 0.5f * hdt * k2);
      float k4 = b2 - a * (y + hdt * k3);
      y += hdt * (1.0f / 6.0f) * (k1 + 2.0f * k2 + 2.0f * k3 + k4);
      yreg = y;
      out_ys[((size_t)(b0 + bb) * 1024 + k) * 32 + jj] = y;
      CFENCE();  // RK4's featL/dtL reads stay before the overwrites below
      if (l < 32) featL[l >> 4][l & 15] = upf;  // u(k+1)
      if (l < 2) dtL[l] = dtpf;                 // dt(k+1)
      {
        const int kn = (k + 2 < 1024) ? k + 2 : 1023;
        if (l < 32)
          upf = u_seq[((size_t)(b0 + (l >> 4)) * 1024 + kn) * 16 + (l & 15)];
        if (l < 2) dtpf = dt_seq[(size_t)(b0 + l) * 1024 + kn];
      }
      float yin = y;
      if (mtfk == tfe - 1)  // (k+1)%tfe==0 -> y_tf(k+1)=y_seq[k] (rare load)
        yin = y_seq[((size_t)(b0 + bb) * 1024 + k) * 32 + jj];
      featL[bb][16 + jj] = yin;
    }
    BAR();  // A: feat(k+1) visible

    // ---- lift x(k+1): 8-lane groups
    if (t < 512) {
      const int o = (t >> 3) & 31, bb = t >> 8, qq = t & 7;
      float a = 0.0f;
#pragma unroll
      for (int i = 0; i < 6; ++i)
        a += featL[bb][6 * qq + i] * liftL[o * 49 + 6 * qq + i];
      a = dpp_add<0xB1>(a); a = dpp_add<0x4E>(a); a = dpp_add<0x104>(a);
      if (qq == 0) { float s = a + lb; xL[bb][o] = s * sigf(s); }
    }
    mtfk = (mtfk + 1 == tfe) ? 0 : mtfk + 1;
    BAR();  // B: x(k+1) visible
  }
}

extern "C" void kernel_launch(void* const* d_in, const int* in_sizes, int n_in,
                              void* d_out, int out_size, void* d_ws,
                              size_t ws_size, hipStream_t stream) {
  (void)in_sizes; (void)n_in; (void)out_size; (void)d_ws; (void)ws_size;
  const float* y0     = (const float*)d_in[0];
  const float* u_seq  = (const float*)d_in[1];
  const float* dt_seq = (const float*)d_in[2];
  const float* y_seq  = (const float*)d_in[3];
  const float* u2y    = (const float*)d_in[4];
  const float* lift_W = (const float*)d_in[5];
  const float* lift_b = (const float*)d_in[6];
  const float* w_ih   = (const float*)d_in[7];
  const float* w_hh   = (const float*)d_in[8];
  const float* b_ih   = (const float*)d_in[9];
  const float* b_hh   = (const float*)d_in[10];
  const float* head_W = (const float*)d_in[11];
  const float* head_b = (const float*)d_in[12];
  const int*   tf_p   = (const int*)d_in[13];

  float* out_ys = (float*)d_out;
  float* out_th = out_ys + (size_t)512 * 1024 * 32;

  odernn_kernel<<<dim3(256), dim3(1024), 0, stream>>>(
      y0, u_seq, dt_seq, y_seq, u2y, lift_W, lift_b, w_ih, w_hh, b_ih, b_hh,
      head_W, head_b, tf_p, out_ys, out_th);
}

// Round 8
// 3020.928 us; speedup vs baseline: 1.7401x; 1.7401x over previous
//
#include <hip/hip_runtime.h>
#include <math.h>

// ODE-RNN forward: B=512, K=1024, U=16, P=32, H=128, L=32, TD=64
// v9 = v1 (3455us, still the measured minimum after 7 variants) with ONE
// change: gate + head dot products emitted as PACKED fp32 pairs
// (v_pk_fma_f32 via <2 x float> ext-vectors + __builtin_elementwise_fma).
// MI355X's 157.3 TF fp32 peak is the PACKED rate; scalar v_fma_f32 is ~half.
// Gates are 240 scalar FMA/wave/step (~960 cy/SIMD of the 3050 busy cy
// measured on v1); packed halves those issue slots AND halves the serial
// FMA accumulation depth (40 -> 20).
//
// Structure lessons (v2-v8, all regressed): fine phase-chunking adds
// LDS-latency segments (v2 5751); 2 blocks/CU impossible - weights 245KB/
// block must be register-resident (v3 18063); barrier drains & staging-load
// latency are NOT the bottleneck (v4 3610 neutral); redundant-compute
// 2-barrier variant trades stalls for 2x issue (v5/v7 3644/4054); 16-wave
// fine-split overflows into AGPR copies, 2.4x VALU issue (v8 5257).
// So: keep v1's exact 6-barrier, 8-wave, 2-batch/block skeleton; cut the
// per-slot cost of the dominant FMA work instead.

typedef float v2f __attribute__((ext_vector_type(2)));

__device__ __forceinline__ v2f mkv2(float a, float b) {
  v2f r; r.x = a; r.y = b; return r;
}

// packed DOT4: float4 v dotted with 2 register pairs (pair base pb)
#define PKD4(acc2, v, w2, pb)                                             \
  acc2 = __builtin_elementwise_fma(mkv2((v).x, (v).y), (w2)[(pb)], acc2); \
  acc2 = __builtin_elementwise_fma(mkv2((v).z, (v).w), (w2)[(pb) + 1], acc2);

__device__ __forceinline__ float sigf(float x) {
  return 1.0f / (1.0f + __expf(-x));
}

__device__ __forceinline__ float tanh_fast(float x) {
  float ax = fabsf(x);
  float e = __expf(2.0f * ax);
  float r = 1.0f - 2.0f / (e + 1.0f);
  return copysignf(r, x);
}

extern "C" __global__ __launch_bounds__(512, 2) void odernn_kernel(
    const float* __restrict__ y0, const float* __restrict__ u_seq,
    const float* __restrict__ dt_seq, const float* __restrict__ y_seq,
    const float* __restrict__ u2y, const float* __restrict__ lift_W,
    const float* __restrict__ lift_b, const float* __restrict__ w_ih,
    const float* __restrict__ w_hh, const float* __restrict__ b_ih,
    const float* __restrict__ b_hh, const float* __restrict__ head_W,
    const float* __restrict__ head_b, const int* __restrict__ tf_p,
    float* __restrict__ out_ys, float* __restrict__ out_th) {
  __shared__ __align__(16) float vecL[2][160];   // [x(32) | h(128)] per batch
  __shared__ __align__(16) float featL[2][48];   // [u(16) | y_in(32)]
  __shared__ float gpart[3][2][3][128];          // q=1..3 partials, r/z/hn
  __shared__ float hpart[8][2][64];              // head partials
  __shared__ float thetaL[2][64];
  __shared__ float dtL[2];
  __shared__ float liftL[32 * 49];               // stride 49: conflict-free
  __shared__ float u2yL[16 * 32];

  const int t = threadIdx.x;
  const int b0 = blockIdx.x * 2;
  const int j = t & 127;   // hidden unit
  const int q = t >> 7;    // k-slice [40q, 40q+40)
  const int tfe = *tf_p;

  // ---- register-resident gate weights as PAIRS: rows j, j+128, j+256;
  // cols 40q..40q+39 -> 20 pairs per gate
  v2f wr2[20], wz2[20], wn2[20];
  {
    const int jr = j, jz = j + 128, jn = j + 256;
#pragma unroll
    for (int cc = 0; cc < 40; ++cc) {
      int c = q * 40 + cc;
      float vr, vz, vn;
      if (c < 32) {
        vr = w_ih[jr * 32 + c];
        vz = w_ih[jz * 32 + c];
        vn = w_ih[jn * 32 + c];
      } else {
        vr = w_hh[jr * 128 + c - 32];
        vz = w_hh[jz * 128 + c - 32];
        vn = w_hh[jn * 128 + c - 32];
      }
      wr2[cc >> 1][cc & 1] = vr;
      wz2[cc >> 1][cc & 1] = vz;
      wn2[cc >> 1][cc & 1] = vn;
    }
  }
  const int ho = t & 63;   // head output
  const int he = t >> 6;   // head k-slice [16he, 16he+16)
  v2f wh2[8];
#pragma unroll
  for (int i = 0; i < 16; ++i)
    wh2[i >> 1][i & 1] = head_W[ho * 128 + he * 16 + i];

  float bR = 0, bZ = 0, bIn = 0, bHn = 0, hb = 0, lb = 0;
  if (t < 128) {
    bR = b_ih[j] + b_hh[j];
    bZ = b_ih[j + 128] + b_hh[j + 128];
    bIn = b_ih[j + 256];
    bHn = b_hh[j + 256];
    hb = head_b[ho];
  }
  if (t < 64) lb = lift_b[t & 31];

  for (int idx = t; idx < 32 * 48; idx += 512)
    liftL[(idx / 48) * 49 + (idx % 48)] = lift_W[idx];
  u2yL[t] = u2y[t];  // 16*32 = 512 elements: one per thread
  if (t < 128) {
    vecL[0][32 + j] = 0.0f;  // h0 = 0
    vecL[1][32 + j] = 0.0f;
  }

  float hreg[2] = {0.0f, 0.0f};
  float yreg = 0.0f;
  if (t < 64) {
    int bb = t >> 5, jj = t & 31;
    yreg = y0[(b0 + bb) * 32 + jj];
  }
  int mtfk = 0;  // k % tfe, incremental (replaces per-step integer mod)
  __syncthreads();

  for (int k = 0; k < 1024; ++k) {
    // ---- phase 1: stage u_k, dt_k, y_in (wave 0 only)
    if (t < 32) {
      int bb = t >> 4, i = t & 15;
      featL[bb][i] = u_seq[((b0 + bb) * 1024 + k) * 16 + i];
    }
    if (t >= 32 && t < 34) {
      dtL[t - 32] = dt_seq[(b0 + t - 32) * 1024 + k];
    }
    if (t < 64) {
      int bb = t >> 5, jj = t & 31;
      float yin = yreg;
      if (k > 0 && mtfk == 0)
        yin = y_seq[((b0 + bb) * 1024 + (k - 1)) * 32 + jj];
      featL[bb][16 + jj] = yin;
    }
    __syncthreads();  // A

    // ---- phase 2: lift  x = silu(feat @ lift_W.T + lift_b)
    if (t < 64) {
      int bb = t >> 5, o = t & 31;
      float a0 = lb, a1 = 0.f, a2 = 0.f, a3 = 0.f;
#pragma unroll
      for (int i = 0; i < 48; i += 4) {
        a0 += featL[bb][i] * liftL[o * 49 + i];
        a1 += featL[bb][i + 1] * liftL[o * 49 + i + 1];
        a2 += featL[bb][i + 2] * liftL[o * 49 + i + 2];
        a3 += featL[bb][i + 3] * liftL[o * 49 + i + 3];
      }
      float acc = (a0 + a1) + (a2 + a3);
      vecL[bb][o] = acc * sigf(acc);
    }
    __syncthreads();  // B

    // ---- phase 3: gates (all 512 threads, both batches) — PACKED pairs
    float accR[2], accZ[2], accN[2], accI[2];
#pragma unroll
    for (int bb = 0; bb < 2; ++bb) {
      v2f aR2 = {0.f, 0.f}, aZ2 = {0.f, 0.f};
      v2f aN2 = {0.f, 0.f}, aI2 = {0.f, 0.f};
      const float4* v4 =
          reinterpret_cast<const float4*>(&vecL[bb][0]) + q * 10;
      if (q == 0) {
#pragma unroll
        for (int i = 0; i < 10; ++i) {
          float4 v = v4[i];
          PKD4(aR2, v, wr2, 2 * i)
          PKD4(aZ2, v, wz2, 2 * i)
          if (i < 8) {
            PKD4(aI2, v, wn2, 2 * i)   // x-part of n-gate (i_n)
          } else {
            PKD4(aN2, v, wn2, 2 * i)   // h-part of n-gate (h_n)
          }
        }
      } else {
#pragma unroll
        for (int i = 0; i < 10; ++i) {
          float4 v = v4[i];
          PKD4(aR2, v, wr2, 2 * i)
          PKD4(aZ2, v, wz2, 2 * i)
          PKD4(aN2, v, wn2, 2 * i)
        }
      }
      float aR = aR2.x + aR2.y;
      float aZ = aZ2.x + aZ2.y;
      float aN = aN2.x + aN2.y;
      float aI = aI2.x + aI2.y;
      if (q > 0) {
        gpart[q - 1][bb][0][j] = aR;
        gpart[q - 1][bb][1][j] = aZ;
        gpart[q - 1][bb][2][j] = aN;
      } else {
        accR[bb] = aR;
        accZ[bb] = aZ;
        accN[bb] = aN;
        accI[bb] = aI;
      }
    }
    __syncthreads();  // C

    // ---- phase 4: GRU elementwise + h update (t<128)
    if (t < 128) {
#pragma unroll
      for (int bb = 0; bb < 2; ++bb) {
        float sR = accR[bb] + bR;
        float sZ = accZ[bb] + bZ;
        float sN = accN[bb] + bHn;  // h_n accumulator (+b_hh)
#pragma unroll
        for (int qq = 0; qq < 3; ++qq) {
          sR += gpart[qq][bb][0][j];
          sZ += gpart[qq][bb][1][j];
          sN += gpart[qq][bb][2][j];
        }
        float r = sigf(sR);
        float z = sigf(sZ);
        float n = tanh_fast(accI[bb] + bIn + r * sN);
        float hn = (1.0f - z) * n + z * hreg[bb];
        hreg[bb] = hn;
        vecL[bb][32 + j] = hn;
      }
    }
    __syncthreads();  // D

    // ---- phase 5: head partials (all threads) — PACKED pairs
#pragma unroll
    for (int bb = 0; bb < 2; ++bb) {
      const float4* h4 =
          reinterpret_cast<const float4*>(&vecL[bb][32]) + he * 4;
      v2f a2 = {0.f, 0.f};
#pragma unroll
      for (int i = 0; i < 4; ++i) {
        float4 v = h4[i];
        PKD4(a2, v, wh2, 2 * i)
      }
      hpart[he][bb][ho] = a2.x + a2.y;
    }
    __syncthreads();  // E

    // ---- phase 6: theta (t<128)
    if (t < 128) {
      int bb = t >> 6, o = t & 63;
      float s = hb;
#pragma unroll
      for (int e = 0; e < 8; ++e) s += hpart[e][bb][o];
      float th = 0.001f + 1.999f * sigf(s);
      thetaL[bb][o] = th;
      out_th[(size_t)((b0 + bb) * 1024 + k) * 64 + o] = th;
    }
    __syncthreads();  // F

    // ---- phase 7: jump + RK4 on y (wave 0 only; reads thetaL after F)
    if (t < 64) {
      int bb = t >> 5, jj = t & 31;
      float y = yreg;
#pragma unroll
      for (int i = 0; i < 16; ++i) y += featL[bb][i] * u2yL[i * 32 + jj];
      float a = thetaL[bb][jj];
      float b2 = thetaL[bb][32 + jj];
      float hdt = dtL[bb];
      float k1 = b2 - a * y;
      float k2 = b2 - a * (y + 0.5f * hdt * k1);
      float k3 = b2 - a * (y + 0.5f * hdt * k2);
      float k4 = b2 - a * (y + hdt * k3);
      y += hdt * (1.0f / 6.0f) * (k1 + 2.0f * k2 + 2.0f * k3 + k4);
      yreg = y;
      out_ys[(size_t)((b0 + bb) * 1024 + k) * 32 + jj] = y;
    }
    mtfk = (mtfk + 1 == tfe) ? 0 : mtfk + 1;
    // no barrier: only wave 0 touches featL/dtL before next A; thetaL/hpart
    // rewritten only after multiple barriers next iteration.
  }
}

extern "C" void kernel_launch(void* const* d_in, const int* in_sizes, int n_in,
                              void* d_out, int out_size, void* d_ws,
                              size_t ws_size, hipStream_t stream) {
  (void)in_sizes; (void)n_in; (void)out_size; (void)d_ws; (void)ws_size;
  const float* y0     = (const float*)d_in[0];
  const float* u_seq  = (const float*)d_in[1];
  const float* dt_seq = (const float*)d_in[2];
  const float* y_seq  = (const float*)d_in[3];
  const float* u2y    = (const float*)d_in[4];
  const float* lift_W = (const float*)d_in[5];
  const float* lift_b = (const float*)d_in[6];
  const float* w_ih   = (const float*)d_in[7];
  const float* w_hh   = (const float*)d_in[8];
  const float* b_ih   = (const float*)d_in[9];
  const float* b_hh   = (const float*)d_in[10];
  const float* head_W = (const float*)d_in[11];
  const float* head_b = (const float*)d_in[12];
  const int*   tf_p   = (const int*)d_in[13];

  float* out_ys = (float*)d_out;
  float* out_th = out_ys + (size_t)512 * 1024 * 32;

  odernn_kernel<<<dim3(256), dim3(512), 0, stream>>>(
      y0, u_seq, dt_seq, y_seq, u2y, lift_W, lift_b, w_ih, w_hh, b_ih, b_hh,
      head_W, head_b, tf_p, out_ys, out_th);
}

// Round 9
// 2750.628 us; speedup vs baseline: 1.9111x; 1.0983x over previous
//
#include <hip/hip_runtime.h>
#include <math.h>

// ODE-RNN forward: B=512, K=1024, U=16, P=32, H=128, L=32, TD=64
// v10 = v9 (3021us: packed fp32 pairs, 1:1 issue->wall conversion proven)
// with the barrier chain cut 6 -> 3 using only silicon-proven pieces:
//  - gates+GRU fused: quad layout (j=t>>2, qj=t&3), 40 cols/lane, partials
//    reduced by 2 quad_perm DPP adds (v7-proven) -> no gpart LDS, no bar C.
//    GRU quad-redundant (intra-wave = free issue); qj==0 writes h.
//  - head+theta fused: 8-lane groups (ho=t>>3, he=t&7), DPP reduce
//    0xB1/0x4E/0x104 (v7/v8-proven) -> no hpart LDS, no bar E.
//  - h double-buffer PADDED HP(c)=c+4*(c>>5) (v7-proven: 2e8 -> 4k
//    conflicts): gate slices at word 36qj and head slices at HP(16he) are
//    bank-disjoint; all reads broadcast across lanes sharing an address.
//  - barrier A removed: featL/dtL wave0-private (stage+lift+RK4 all t<64);
//    same-wave LDS ordering is compiler-guaranteed. u/dt reg-prefetch (v4).
//  - packed lift (24 pk-FMA) and packed u2y jump (8 pk-FMA).
// Step: B(x ready) -> gates+DPP+GRU -> D(h ready) -> head+DPP+theta ->
//       E(theta ready) -> wave0: RK4+store+stage(k+1)+lift(k+1) -> B.
// Failure modes avoided (each measured in v2/v5/v7/v8): no added phases,
// no cross-wave redundant compute, no unpadded strided LDS, same register
// budget as v9 (112 VGPR reported).

typedef float v2f __attribute__((ext_vector_type(2)));

__device__ __forceinline__ v2f mkv2(float a, float b) {
  v2f r; r.x = a; r.y = b; return r;
}

// packed DOT4: float4 v dotted with 2 register pairs (pair base pb)
#define PKD4(acc2, v, w2, pb)                                             \
  acc2 = __builtin_elementwise_fma(mkv2((v).x, (v).y), (w2)[(pb)], acc2); \
  acc2 = __builtin_elementwise_fma(mkv2((v).z, (v).w), (w2)[(pb) + 1], acc2);

__device__ __forceinline__ float sigf(float x) {
  return 1.0f / (1.0f + __expf(-x));
}

__device__ __forceinline__ float tanh_fast(float x) {
  float ax = fabsf(x);
  float e = __expf(2.0f * ax);
  float r = 1.0f - 2.0f / (e + 1.0f);
  return copysignf(r, x);
}

// x + (x cross-lane via DPP), pure VALU pipe.
// 0xB1 quad_perm xor1; 0x4E quad_perm xor2; 0x104 row_shl:4 (dst i <- src
// i+4; result valid at row-lanes <12, our leaders are at row-lanes 0/8).
template <int CTRL>
__device__ __forceinline__ float dpp_add(float x) {
  int s = __float_as_int(x);
  int r = __builtin_amdgcn_update_dpp(s, s, CTRL, 0xF, 0xF, false);
  return x + __int_as_float(r);
}

// padded h index: +4 words after every 32 cols (slice qj starts at 36qj)
#define HP(c) ((c) + 4 * ((c) >> 5))
#define HROW 144  // 128 + 12 pad, 16B multiple

extern "C" __global__ __launch_bounds__(512, 2) void odernn_kernel(
    const float* __restrict__ y0, const float* __restrict__ u_seq,
    const float* __restrict__ dt_seq, const float* __restrict__ y_seq,
    const float* __restrict__ u2y, const float* __restrict__ lift_W,
    const float* __restrict__ lift_b, const float* __restrict__ w_ih,
    const float* __restrict__ w_hh, const float* __restrict__ b_ih,
    const float* __restrict__ b_hh, const float* __restrict__ head_W,
    const float* __restrict__ head_b, const int* __restrict__ tf_p,
    float* __restrict__ out_ys, float* __restrict__ out_th) {
  __shared__ __align__(16) float hbufP[2][2][HROW];  // h dbuf, HP-padded
  __shared__ __align__(16) float xL[2][32];          // lifted x
  __shared__ __align__(16) float featL[2][48];       // [u(16)|y_in(32)] w0-priv
  __shared__ float thetaL[2][64];
  __shared__ float dtL[2];                           // wave0-private
  __shared__ float liftL[32 * 49];                   // stride 49 conflict-free
  __shared__ float u2yL[512];

  const int t = threadIdx.x;
  const int b0 = blockIdx.x * 2;
  const int j = t >> 2;    // hidden unit 0..127 (4 adjacent lanes per unit)
  const int qj = t & 3;    // col slice: x[8qj..8qj+8) + h[32qj..32qj+32)
  const int ho = t >> 3;   // head output 0..63 (8 adjacent lanes per output)
  const int he = t & 7;    // head col slice: h[16he..16he+16)
  const int tfe = *tf_p;

  // ---- register-resident gate weights as pairs (20 v2f per gate):
  // pairs 0..3 = x-cols 8qj..8qj+8; pairs 4..19 = h-cols 32qj..32qj+32
  v2f wr2[20], wz2[20], wn2[20];
  {
    const int jr = j, jz = j + 128, jn = j + 256;
#pragma unroll
    for (int cc = 0; cc < 8; ++cc) {
      const int c = 8 * qj + cc;
      wr2[cc >> 1][cc & 1] = w_ih[jr * 32 + c];
      wz2[cc >> 1][cc & 1] = w_ih[jz * 32 + c];
      wn2[cc >> 1][cc & 1] = w_ih[jn * 32 + c];
    }
#pragma unroll
    for (int cc = 0; cc < 32; ++cc) {
      const int c = 32 * qj + cc;
      wr2[4 + (cc >> 1)][cc & 1] = w_hh[jr * 128 + c];
      wz2[4 + (cc >> 1)][cc & 1] = w_hh[jz * 128 + c];
      wn2[4 + (cc >> 1)][cc & 1] = w_hh[jn * 128 + c];
    }
  }
  v2f wh2[8];
#pragma unroll
  for (int i = 0; i < 16; ++i)
    wh2[i >> 1][i & 1] = head_W[ho * 128 + 16 * he + i];

  const float bR = b_ih[j] + b_hh[j];
  const float bZ = b_ih[j + 128] + b_hh[j + 128];
  const float bIn = b_ih[j + 256];
  const float bHn = b_hh[j + 256];
  const float hb = head_b[ho];
  const float lb = lift_b[t & 31];

  for (int idx = t; idx < 32 * 48; idx += 512)
    liftL[(idx / 48) * 49 + (idx % 48)] = lift_W[idx];
  u2yL[t] = u2y[t];
  for (int idx = t; idx < 2 * 2 * HROW; idx += 512)
    (&hbufP[0][0][0])[idx] = 0.0f;  // zero both h buffers incl. padding

  float hreg[2] = {0.0f, 0.0f};  // quad-redundant h state for unit j
  float yreg = 0.0f;
  float upf = 0.0f, dtpf = 0.0f;
  if (t < 64) yreg = y0[(b0 + (t >> 5)) * 32 + (t & 31)];

  __syncthreads();  // liftL/u2yL/hbufP-zero visible

  // ---- prologue (wave0): stage feat(0), prefetch k=1, lift x(0)
  if (t < 64) {
    const int bb = t >> 5, jj = t & 31;
    if (t < 32)
      featL[t >> 4][t & 15] =
          u_seq[((size_t)(b0 + (t >> 4)) * 1024 + 0) * 16 + (t & 15)];
    if (t >= 32 && t < 34) dtL[t - 32] = dt_seq[(size_t)(b0 + t - 32) * 1024];
    featL[bb][16 + jj] = yreg;  // k=0: no teacher forcing
    if (t < 32)
      upf = u_seq[((size_t)(b0 + (t >> 4)) * 1024 + 1) * 16 + (t & 15)];
    if (t >= 32 && t < 34) dtpf = dt_seq[(size_t)(b0 + t - 32) * 1024 + 1];
    // lift x(0), packed pairs
    v2f a2 = {0.f, 0.f};
#pragma unroll
    for (int i = 0; i < 48; i += 2)
      a2 = __builtin_elementwise_fma(
          mkv2(featL[bb][i], featL[bb][i + 1]),
          mkv2(liftL[jj * 49 + i], liftL[jj * 49 + i + 1]), a2);
    float acc = a2.x + a2.y + lb;
    xL[bb][jj] = acc * sigf(acc);
  }
  int mtfk = 0;  // k % tfe, incremental
  __syncthreads();  // B(0): x(0) visible

  for (int k = 0; k < 1024; ++k) {
    const int rp = k & 1;  // gates read hbufP[rp]=h(k-1); write hbufP[rp^1]

    // ---- phase G: gates (packed) + quad DPP reduce + GRU, all threads
#pragma unroll
    for (int bb = 0; bb < 2; ++bb) {
      v2f aR2 = {0.f, 0.f}, aZ2 = {0.f, 0.f};
      v2f aI2 = {0.f, 0.f}, aN2 = {0.f, 0.f};
      const float4* xv = reinterpret_cast<const float4*>(&xL[bb][8 * qj]);
      {
        float4 v = xv[0];
        PKD4(aR2, v, wr2, 0) PKD4(aZ2, v, wz2, 0) PKD4(aI2, v, wn2, 0)
        v = xv[1];
        PKD4(aR2, v, wr2, 2) PKD4(aZ2, v, wz2, 2) PKD4(aI2, v, wn2, 2)
      }
      const float4* hv =
          reinterpret_cast<const float4*>(&hbufP[rp][bb][36 * qj]);
#pragma unroll
      for (int i = 0; i < 8; ++i) {
        float4 v = hv[i];
        PKD4(aR2, v, wr2, 4 + 2 * i)
        PKD4(aZ2, v, wz2, 4 + 2 * i)
        PKD4(aN2, v, wn2, 4 + 2 * i)
      }
      float aR = aR2.x + aR2.y;
      float aZ = aZ2.x + aZ2.y;
      float aI = aI2.x + aI2.y;
      float aN = aN2.x + aN2.y;
      // quad reduce (xor1, xor2): all 4 lanes end with full sums
      aR = dpp_add<0xB1>(aR); aR = dpp_add<0x4E>(aR);
      aZ = dpp_add<0xB1>(aZ); aZ = dpp_add<0x4E>(aZ);
      aI = dpp_add<0xB1>(aI); aI = dpp_add<0x4E>(aI);
      aN = dpp_add<0xB1>(aN); aN = dpp_add<0x4E>(aN);
      // GRU (quad-redundant, intra-wave = free); qj==0 writes h
      float r = sigf(aR + bR);
      float z = sigf(aZ + bZ);
      float n = tanh_fast(aI + bIn + r * (aN + bHn));
      float hn = (1.0f - z) * n + z * hreg[bb];
      hreg[bb] = hn;
      if (qj == 0) hbufP[rp ^ 1][bb][HP(j)] = hn;
    }
    __syncthreads();  // D: h(k) visible

    // ---- phase H: head (packed) + 8-lane DPP reduce + theta, all threads
    {
      float s[2];
#pragma unroll
      for (int bb = 0; bb < 2; ++bb) {
        const float4* h4 =
            reinterpret_cast<const float4*>(&hbufP[rp ^ 1][bb][HP(16 * he)]);
        v2f a2 = {0.f, 0.f};
#pragma unroll
        for (int i = 0; i < 4; ++i) {
          float4 v = h4[i];
          PKD4(a2, v, wh2, 2 * i)
        }
        float a = a2.x + a2.y;
        a = dpp_add<0xB1>(a); a = dpp_add<0x4E>(a); a = dpp_add<0x104>(a);
        s[bb] = a;
      }
      if (he == 0) {  // row-lanes 0/8: full 8-lane sum valid after row_shl:4
#pragma unroll
        for (int bb = 0; bb < 2; ++bb) {
          float th = 0.001f + 1.999f * sigf(s[bb] + hb);
          thetaL[bb][ho] = th;
          out_th[((size_t)(b0 + bb) * 1024 + k) * 64 + ho] = th;
        }
      }
    }
    __syncthreads();  // E: thetaL visible

    // ---- phase Y (wave0): jump(packed) + RK4 + store + stage(k+1) + lift
    if (t < 64) {
      const int bb = t >> 5, jj = t & 31;
      v2f y2 = {0.f, 0.f};
#pragma unroll
      for (int i = 0; i < 16; i += 2)
        y2 = __builtin_elementwise_fma(
            mkv2(featL[bb][i], featL[bb][i + 1]),
            mkv2(u2yL[i * 32 + jj], u2yL[(i + 1) * 32 + jj]), y2);
      float y = yreg + y2.x + y2.y;
      float a = thetaL[bb][jj];
      float b2 = thetaL[bb][32 + jj];
      float hdt = dtL[bb];
      float k1 = b2 - a * y;
      float k2 = b2 - a * (y + 0.5f * hdt * k1);
      float k3 = b2 - a * (y + 0.5f * hdt * k2);
      float k4 = b2 - a * (y + hdt * k3);
      y += hdt * (1.0f / 6.0f) * (k1 + 2.0f * k2 + 2.0f * k3 + k4);
      yreg = y;
      out_ys[((size_t)(b0 + bb) * 1024 + k) * 32 + jj] = y;
      // stage k+1 (same wave; compiler orders featL/dtL reads above via lgkm)
      if (t < 32) featL[t >> 4][t & 15] = upf;
      if (t >= 32 && t < 34) dtL[t - 32] = dtpf;
      {
        const int kn = (k + 2 < 1024) ? k + 2 : 1023;
        if (t < 32)
          upf = u_seq[((size_t)(b0 + (t >> 4)) * 1024 + kn) * 16 + (t & 15)];
        if (t >= 32 && t < 34)
          dtpf = dt_seq[(size_t)(b0 + t - 32) * 1024 + kn];
      }
      float yin = y;
      if (mtfk == tfe - 1)  // (k+1)%tfe==0 -> y_tf(k+1)=y_seq[k] (1 in 50)
        yin = y_seq[((size_t)(b0 + bb) * 1024 + k) * 32 + jj];
      featL[bb][16 + jj] = yin;
      // lift x(k+1), packed pairs (same wave reads the stage above)
      v2f a2 = {0.f, 0.f};
#pragma unroll
      for (int i = 0; i < 48; i += 2)
        a2 = __builtin_elementwise_fma(
            mkv2(featL[bb][i], featL[bb][i + 1]),
            mkv2(liftL[jj * 49 + i], liftL[jj * 49 + i + 1]), a2);
      float acc = a2.x + a2.y + lb;
      xL[bb][jj] = acc * sigf(acc);
    }
    mtfk = (mtfk + 1 == tfe) ? 0 : mtfk + 1;
    __syncthreads();  // B(k+1): x(k+1) visible
  }
}

extern "C" void kernel_launch(void* const* d_in, const int* in_sizes, int n_in,
                              void* d_out, int out_size, void* d_ws,
                              size_t ws_size, hipStream_t stream) {
  (void)in_sizes; (void)n_in; (void)out_size; (void)d_ws; (void)ws_size;
  const float* y0     = (const float*)d_in[0];
  const float* u_seq  = (const float*)d_in[1];
  const float* dt_seq = (const float*)d_in[2];
  const float* y_seq  = (const float*)d_in[3];
  const float* u2y    = (const float*)d_in[4];
  const float* lift_W = (const float*)d_in[5];
  const float* lift_b = (const float*)d_in[6];
  const float* w_ih   = (const float*)d_in[7];
  const float* w_hh   = (const float*)d_in[8];
  const float* b_ih   = (const float*)d_in[9];
  const float* b_hh   = (const float*)d_in[10];
  const float* head_W = (const float*)d_in[11];
  const float* head_b = (const float*)d_in[12];
  const int*   tf_p   = (const int*)d_in[13];

  float* out_ys = (float*)d_out;
  float* out_th = out_ys + (size_t)512 * 1024 * 32;

  odernn_kernel<<<dim3(256), dim3(512), 0, stream>>>(
      y0, u_seq, dt_seq, y_seq, u2y, lift_W, lift_b, w_ih, w_hh, b_ih, b_hh,
      head_W, head_b, tf_p, out_ys, out_th);
}